// Round 5
// baseline (102.981 us; speedup 1.0000x reference)
//
#include <hip/hip_runtime.h>
#include <math.h>

#define NS 256
#define EMB 120
#define NBLK 60
#define MODES 16
#define NPH 8

typedef float v2f __attribute__((ext_vector_type(2)));

// complex mul
__device__ __forceinline__ v2f cmul(v2f a, v2f b) {
    v2f axx = {a.x, a.x};
    v2f nyy = {-a.y, a.y};
    v2f byx = {b.y, b.x};
    return axx * b + nyy * byx;   // {ax*bx - ay*by, ax*by + ay*bx}
}
// r = conj(a)*b + c
__device__ __forceinline__ v2f cfma_conj(v2f a, v2f b, v2f c) {
    v2f axx = {a.x, a.x};
    v2f pyy = {a.y, -a.y};
    v2f byx = {b.y, b.x};
    return axx * b + (pyy * byx + c);
}

// Cross-lane xor within quad via DPP quad_perm (VALU, not LDS pipe).
// xor1: [1,0,3,2] -> ctrl 0xB1 ; xor2: [2,3,0,1] -> ctrl 0x4E
__device__ __forceinline__ float dpp_xor1(float x) {
    return __builtin_bit_cast(float,
        __builtin_amdgcn_mov_dpp(__builtin_bit_cast(int, x), 0xB1, 0xF, 0xF, true));
}
__device__ __forceinline__ float dpp_xor2(float x) {
    return __builtin_bit_cast(float,
        __builtin_amdgcn_mov_dpp(__builtin_bit_cast(int, x), 0x4E, 0xF, 0xF, true));
}

// MEASUREMENT ROUND: kernels are byte-identical to the round-0 anchor
// (best measured total, 75.6us). perm_kernel is launched 3x (pure,
// idempotent function of Vws -> outK, so replays are correctness-neutral).
// dur_us_new - 76.1 = 2*(perm_duration + node_gap): decides whether the
// remaining ~26us of controllable time is perm, emb, or launch-gap bound.

// Kernel A: x_emb = sigmoid(x@W.T+b); build V = U[:, :, 0:8] per sample.
__global__ __launch_bounds__(128) void emb_v_kernel(
    const float* __restrict__ x, const float* __restrict__ W,
    const float* __restrict__ bias, float* __restrict__ out_emb,
    float2* __restrict__ Vws)
{
    const int s = blockIdx.x;
    const int t = threadIdx.x;
    __shared__ float emb[EMB];
    __shared__ float ctA[NBLK], stA[NBLK], exA[NBLK], eyA[NBLK];

    if (t < EMB) {
        const float* xr = x + s * 64;
        const float* wr = W + t * 64;
        float acc = bias[t];
        #pragma unroll
        for (int k = 0; k < 64; ++k) acc = fmaf(xr[k], wr[k], acc);
        float e = 1.0f / (1.0f + expf(-acc));
        emb[t] = e;
        out_emb[s * EMB + t] = e;
    }
    __syncthreads();

    if (t < NBLK) {
        float th = emb[2 * t]     * 1.57079632679489662f;  // pi/2
        float ph = emb[2 * t + 1] * 6.28318530717958648f;  // 2*pi
        float st, ct, sp, cp;
        sincosf(th, &st, &ct);
        sincosf(ph, &sp, &cp);
        ctA[t] = ct; stA[t] = st; exA[t] = cp; eyA[t] = sp;
    }
    __syncthreads();

    if (t < NPH) {
        const int c = t;  // column 0..7
        float2 u[MODES];
        #pragma unroll
        for (int m = 0; m < MODES; ++m) {
            u[m].x = (m == c) ? 1.0f : 0.0f;
            u[m].y = 0.0f;
        }
        int bi = 0;
        #pragma unroll
        for (int d = 0; d < 8; ++d) {
            const int off = d & 1;
            const int nb = 8 - off;
            #pragma unroll
            for (int k = 0; k < nb; ++k) {
                float ct = ctA[bi], st = stA[bi], ex = exA[bi], ey = eyA[bi];
                ++bi;
                const int r0 = off + 2 * k;
                float2 u0 = u[r0], u1 = u[r0 + 1];
                float2 n0, n1;
                n0.x = ex * ct * u0.x - ey * ct * u0.y - st * u1.x;
                n0.y = ex * ct * u0.y + ey * ct * u0.x - st * u1.y;
                n1.x = ex * st * u0.x - ey * st * u0.y + ct * u1.x;
                n1.y = ex * st * u0.y + ey * st * u0.x + ct * u1.y;
                u[r0] = n0; u[r0 + 1] = n1;
            }
        }
        #pragma unroll
        for (int m = 0; m < MODES; ++m)
            Vws[(s * MODES + m) * NPH + c] = u[m];
    }
}

// Kernel B: upper-triangular tiles only (K symmetric). 528 blocks of 8x8 pairs.
// 4 threads/pair = (row-half h) x (delta7-half e); cross-lane via DPP quad_perm.
__global__ __launch_bounds__(256, 2) void perm_kernel(
    const float2* __restrict__ Vws, float* __restrict__ outK)
{
    __shared__ float2 sva[8][132];
    __shared__ float2 svb[8][132];

    // triangular decode: blockIdx -> (ta, tb), ta <= tb
    const int L = blockIdx.x;
    int t = (int)((65.0f - sqrtf(4225.0f - 8.0f * (float)L)) * 0.5f);
    while (t * (65 - t) / 2 > L) --t;
    while ((t + 1) * (65 - (t + 1)) / 2 <= L) ++t;
    const int ta = t;
    const int tb = ta + (L - t * (65 - t) / 2);

    const int tid = threadIdx.x;
    const float4* srcA = (const float4*)(Vws + (size_t)ta * 8 * 128);
    const float4* srcB = (const float4*)(Vws + (size_t)tb * 8 * 128);
    #pragma unroll
    for (int r = 0; r < 2; ++r) {
        int idx = r * 256 + tid;       // 0..511
        int row = idx >> 6;
        int c4  = idx & 63;
        *(float4*)&sva[row][c4 * 2] = srcA[idx];
        *(float4*)&svb[row][c4 * 2] = srcB[idx];
    }
    __syncthreads();

    const int p   = tid >> 2;    // pair 0..63 (quad-aligned lanes)
    const int sub = tid & 3;
    const int h   = sub & 1;     // row half
    const int e   = sub >> 1;    // delta7 half
    const int pa  = p >> 3;
    const int pb  = p & 7;

    // ---- build own 2 rows: rows 4h+2e, 4h+2e+1 of G = Va^H Vb ----
    v2f Go[2][8];
    #pragma unroll
    for (int i = 0; i < 2; ++i)
        #pragma unroll
        for (int j = 0; j < 8; ++j) Go[i][j] = (v2f){0.f, 0.f};

    #pragma unroll 2
    for (int m = 0; m < 16; ++m) {
        float4 va4 = *(const float4*)&sva[pa][m * 8 + 4 * h + 2 * e];
        v2f a0 = {va4.x, va4.y};
        v2f a1 = {va4.z, va4.w};
        v2f vb[8];
        #pragma unroll
        for (int jj = 0; jj < 4; ++jj) {
            float4 b4 = *(const float4*)&svb[pb][m * 8 + 2 * jj];
            vb[2 * jj]     = (v2f){b4.x, b4.y};
            vb[2 * jj + 1] = (v2f){b4.z, b4.w};
        }
        #pragma unroll
        for (int j = 0; j < 8; ++j) {
            Go[0][j] = cfma_conj(a0, vb[j], Go[0][j]);
            Go[1][j] = cfma_conj(a1, vb[j], Go[1][j]);
        }
    }

    // ---- exchange 2 rows with delta-partner (xor 2) via DPP ----
    v2f Gp[2][8];
    #pragma unroll
    for (int i = 0; i < 2; ++i)
        #pragma unroll
        for (int j = 0; j < 8; ++j) {
            Gp[i][j].x = dpp_xor2(Go[i][j].x);
            Gp[i][j].y = dpp_xor2(Go[i][j].y);
        }

    // ---- rs init: delta = (+1,...,+1, sgn_e) ----
    const float sgn = 1.0f - 2.0f * (float)e;
    const v2f sgnv = {sgn, sgn};
    v2f rs[4];
    #pragma unroll
    for (int r = 0; r < 2; ++r) {
        {
            v2f s = ((Go[r][0] + Go[r][1]) + (Go[r][2] + Go[r][3]))
                  + ((Go[r][4] + Go[r][5]) + Go[r][6]);
            rs[r] = sgnv * Go[r][7] + s;
        }
        {
            v2f s = ((Gp[r][0] + Gp[r][1]) + (Gp[r][2] + Gp[r][3]))
                  + ((Gp[r][4] + Gp[r][5]) + Gp[r][6]);
            rs[2 + r] = sgnv * Gp[r][7] + s;
        }
    }

    v2f acc;

#define TREE(OUT) do {                                                \
        v2f t01 = cmul(rs[0], rs[1]);                                 \
        v2f t23 = cmul(rs[2], rs[3]);                                 \
        v2f half_ = cmul(t01, t23);                                   \
        v2f oth;                                                      \
        oth.x = dpp_xor1(half_.x);                                    \
        oth.y = dpp_xor1(half_.y);                                    \
        OUT = cmul(half_, oth);                                       \
    } while (0)

#define UPD(J, S) do {                                                \
        const v2f sv = {(S), (S)};                                    \
        rs[0] = sv * Go[0][J] + rs[0];                                \
        rs[1] = sv * Go[1][J] + rs[1];                                \
        rs[2] = sv * Gp[0][J] + rs[2];                                \
        rs[3] = sv * Gp[1][J] + rs[3];                                \
    } while (0)

#define TERM(TS) do {                                                 \
        v2f fullp; TREE(fullp);                                       \
        const v2f tv = {(TS), (TS)};                                  \
        acc = tv * fullp + acc;                                       \
    } while (0)

    TREE(acc);                              // t=0, sign +
    UPD(1, -2.f); TERM(-1.f);               // t=1
    UPD(2, -2.f); TERM( 1.f);               // t=2
    UPD(1,  2.f); TERM(-1.f);               // t=3
    UPD(3, -2.f); TERM( 1.f);               // t=4
    UPD(1, -2.f); TERM(-1.f);               // t=5
    UPD(2,  2.f); TERM( 1.f);               // t=6
    UPD(1,  2.f); TERM(-1.f);               // t=7
    UPD(4, -2.f); TERM( 1.f);               // t=8
    UPD(1, -2.f); TERM(-1.f);               // t=9
    UPD(2, -2.f); TERM( 1.f);               // t=10
    UPD(1,  2.f); TERM(-1.f);               // t=11
    UPD(3,  2.f); TERM( 1.f);               // t=12
    UPD(1, -2.f); TERM(-1.f);               // t=13
    UPD(2,  2.f); TERM( 1.f);               // t=14
    UPD(1,  2.f); TERM(-1.f);               // t=15
    UPD(5, -2.f); TERM( 1.f);               // t=16
    UPD(1, -2.f); TERM(-1.f);               // t=17
    UPD(2, -2.f); TERM( 1.f);               // t=18
    UPD(1,  2.f); TERM(-1.f);               // t=19
    UPD(3, -2.f); TERM( 1.f);               // t=20
    UPD(1, -2.f); TERM(-1.f);               // t=21
    UPD(2,  2.f); TERM( 1.f);               // t=22
    UPD(1,  2.f); TERM(-1.f);               // t=23
    UPD(4,  2.f); TERM( 1.f);               // t=24
    UPD(1, -2.f); TERM(-1.f);               // t=25
    UPD(2, -2.f); TERM( 1.f);               // t=26
    UPD(1,  2.f); TERM(-1.f);               // t=27
    UPD(3,  2.f); TERM( 1.f);               // t=28
    UPD(1, -2.f); TERM(-1.f);               // t=29
    UPD(2,  2.f); TERM( 1.f);               // t=30
    UPD(1,  2.f); TERM(-1.f);               // t=31
    UPD(6, -2.f); TERM( 1.f);               // t=32
    UPD(1, -2.f); TERM(-1.f);               // t=33
    UPD(2, -2.f); TERM( 1.f);               // t=34
    UPD(1,  2.f); TERM(-1.f);               // t=35
    UPD(3, -2.f); TERM( 1.f);               // t=36
    UPD(1, -2.f); TERM(-1.f);               // t=37
    UPD(2,  2.f); TERM( 1.f);               // t=38
    UPD(1,  2.f); TERM(-1.f);               // t=39
    UPD(4, -2.f); TERM( 1.f);               // t=40
    UPD(1, -2.f); TERM(-1.f);               // t=41
    UPD(2, -2.f); TERM( 1.f);               // t=42
    UPD(1,  2.f); TERM(-1.f);               // t=43
    UPD(3,  2.f); TERM( 1.f);               // t=44
    UPD(1, -2.f); TERM(-1.f);               // t=45
    UPD(2,  2.f); TERM( 1.f);               // t=46
    UPD(1,  2.f); TERM(-1.f);               // t=47
    UPD(5,  2.f); TERM( 1.f);               // t=48
    UPD(1, -2.f); TERM(-1.f);               // t=49
    UPD(2, -2.f); TERM( 1.f);               // t=50
    UPD(1,  2.f); TERM(-1.f);               // t=51
    UPD(3, -2.f); TERM( 1.f);               // t=52
    UPD(1, -2.f); TERM(-1.f);               // t=53
    UPD(2,  2.f); TERM( 1.f);               // t=54
    UPD(1,  2.f); TERM(-1.f);               // t=55
    UPD(4,  2.f); TERM( 1.f);               // t=56
    UPD(1, -2.f); TERM(-1.f);               // t=57
    UPD(2, -2.f); TERM( 1.f);               // t=58
    UPD(1,  2.f); TERM(-1.f);               // t=59
    UPD(3,  2.f); TERM( 1.f);               // t=60
    UPD(1, -2.f); TERM(-1.f);               // t=61
    UPD(2,  2.f); TERM( 1.f);               // t=62
    UPD(1,  2.f); TERM(-1.f);               // t=63
#undef UPD
#undef TERM
#undef TREE

    // fold delta7 sign, then combine the two delta-halves (xor 2, DPP)
    float ax = sgn * acc.x, ay = sgn * acc.y;
    ax += dpp_xor2(ax);
    ay += dpp_xor2(ay);

    if (sub == 0) {
        const int a = ta * 8 + pa;
        const int b = tb * 8 + pb;
        float K = fmaf(ax, ax, ay * ay) * (1.0f / 16384.0f);
        if (a == b) K = 1.0f;
        outK[a * 256 + b] = K;
        outK[b * 256 + a] = K;   // Hermitian symmetry
    }
}

extern "C" void kernel_launch(void* const* d_in, const int* in_sizes, int n_in,
                              void* d_out, int out_size, void* d_ws, size_t ws_size,
                              hipStream_t stream) {
    const float* x    = (const float*)d_in[0];   // 256*64
    const float* W    = (const float*)d_in[1];   // 120*64
    const float* bias = (const float*)d_in[2];   // 120
    float* out     = (float*)d_out;
    float* out_emb = out;              // 256*120
    float* outK    = out + NS * EMB;   // 256*256
    float2* Vws    = (float2*)d_ws;    // 256*16*8 float2 = 256 KB

    emb_v_kernel<<<NS, 128, 0, stream>>>(x, W, bias, out_emb, Vws);
    // perm launched 3x: pure & idempotent, so replays are correctness-neutral.
    // (dur_us - 76.1)/2 = perm_duration + node_gap -> decides round 6.
    perm_kernel<<<528, 256, 0, stream>>>(Vws, outK);
    perm_kernel<<<528, 256, 0, stream>>>(Vws, outK);
    perm_kernel<<<528, 256, 0, stream>>>(Vws, outK);
}

// Round 6
// 75.154 us; speedup vs baseline: 1.3703x; 1.3703x over previous
//
#include <hip/hip_runtime.h>
#include <math.h>

#define NS 256
#define EMB 120
#define NBLK 60
#define MODES 16
#define NPH 8

typedef float v2f __attribute__((ext_vector_type(2)));

// complex mul
__device__ __forceinline__ v2f cmul(v2f a, v2f b) {
    v2f axx = {a.x, a.x};
    v2f nyy = {-a.y, a.y};
    v2f byx = {b.y, b.x};
    return axx * b + nyy * byx;   // {ax*bx - ay*by, ax*by + ay*bx}
}
// r = conj(a)*b + c
__device__ __forceinline__ v2f cfma_conj(v2f a, v2f b, v2f c) {
    v2f axx = {a.x, a.x};
    v2f pyy = {a.y, -a.y};
    v2f byx = {b.y, b.x};
    return axx * b + (pyy * byx + c);
}

// Cross-lane xor within quad via DPP quad_perm (VALU, not LDS pipe).
// xor1: [1,0,3,2] -> ctrl 0xB1 ; xor2: [2,3,0,1] -> ctrl 0x4E
__device__ __forceinline__ float dpp_xor1(float x) {
    return __builtin_bit_cast(float,
        __builtin_amdgcn_mov_dpp(__builtin_bit_cast(int, x), 0xB1, 0xF, 0xF, true));
}
__device__ __forceinline__ float dpp_xor2(float x) {
    return __builtin_bit_cast(float,
        __builtin_amdgcn_mov_dpp(__builtin_bit_cast(int, x), 0x4E, 0xF, 0xF, true));
}
// xor4 crosses quads: ds_swizzle butterfly, offset = (xor_mask<<10)|0x1F
__device__ __forceinline__ float swz_xor4(float x) {
    return __builtin_bit_cast(float,
        __builtin_amdgcn_ds_swizzle(__builtin_bit_cast(int, x), 0x101F));
}

// Kernel A: byte-identical to the round-0 anchor.
__global__ __launch_bounds__(128) void emb_v_kernel(
    const float* __restrict__ x, const float* __restrict__ W,
    const float* __restrict__ bias, float* __restrict__ out_emb,
    float2* __restrict__ Vws)
{
    const int s = blockIdx.x;
    const int t = threadIdx.x;
    __shared__ float emb[EMB];
    __shared__ float ctA[NBLK], stA[NBLK], exA[NBLK], eyA[NBLK];

    if (t < EMB) {
        const float* xr = x + s * 64;
        const float* wr = W + t * 64;
        float acc = bias[t];
        #pragma unroll
        for (int k = 0; k < 64; ++k) acc = fmaf(xr[k], wr[k], acc);
        float e = 1.0f / (1.0f + expf(-acc));
        emb[t] = e;
        out_emb[s * EMB + t] = e;
    }
    __syncthreads();

    if (t < NBLK) {
        float th = emb[2 * t]     * 1.57079632679489662f;  // pi/2
        float ph = emb[2 * t + 1] * 6.28318530717958648f;  // 2*pi
        float st, ct, sp, cp;
        sincosf(th, &st, &ct);
        sincosf(ph, &sp, &cp);
        ctA[t] = ct; stA[t] = st; exA[t] = cp; eyA[t] = sp;
    }
    __syncthreads();

    if (t < NPH) {
        const int c = t;  // column 0..7
        float2 u[MODES];
        #pragma unroll
        for (int m = 0; m < MODES; ++m) {
            u[m].x = (m == c) ? 1.0f : 0.0f;
            u[m].y = 0.0f;
        }
        int bi = 0;
        #pragma unroll
        for (int d = 0; d < 8; ++d) {
            const int off = d & 1;
            const int nb = 8 - off;
            #pragma unroll
            for (int k = 0; k < nb; ++k) {
                float ct = ctA[bi], st = stA[bi], ex = exA[bi], ey = eyA[bi];
                ++bi;
                const int r0 = off + 2 * k;
                float2 u0 = u[r0], u1 = u[r0 + 1];
                float2 n0, n1;
                n0.x = ex * ct * u0.x - ey * ct * u0.y - st * u1.x;
                n0.y = ex * ct * u0.y + ey * ct * u0.x - st * u1.y;
                n1.x = ex * st * u0.x - ey * st * u0.y + ct * u1.x;
                n1.y = ex * st * u0.y + ey * st * u0.x + ct * u1.y;
                u[r0] = n0; u[r0 + 1] = n1;
            }
        }
        #pragma unroll
        for (int m = 0; m < MODES; ++m)
            Vws[(s * MODES + m) * NPH + c] = u[m];
    }
}

// Kernel B: Glynn permanent, 8 lanes/pair (R2 structure) WITHOUT work
// duplication: the f lane bit splits the G-build m-loop (f=0: m 0..7,
// f=1: m 8..15; combined via one ds_swizzle xor-4 add per G element)
// and then serves as the delta6 Glynn bit exactly as in R2's verified
// ladder. Per-thread inst ~1050 (vs R2's ~1400, R0's ~2000); device
// total +5% vs R0 for 2x the waves/SIMD (4.125 blocks/CU, tail 1.21).
__global__ __launch_bounds__(256, 4) void perm_kernel(
    const float2* __restrict__ Vws, float* __restrict__ outK)
{
    __shared__ float2 sva[8][132];
    __shared__ float2 svb[8][132];

    // triangular decode: blockIdx>>1 -> (ta, tb), ta <= tb; blockIdx&1 -> pa half
    const int L  = blockIdx.x >> 1;
    const int hb = blockIdx.x & 1;
    int t = (int)((65.0f - sqrtf(4225.0f - 8.0f * (float)L)) * 0.5f);
    while (t * (65 - t) / 2 > L) --t;
    while ((t + 1) * (65 - (t + 1)) / 2 <= L) ++t;
    const int ta = t;
    const int tb = ta + (L - t * (65 - t) / 2);

    const int tid = threadIdx.x;
    const float4* srcA = (const float4*)(Vws + (size_t)ta * 8 * 128);
    const float4* srcB = (const float4*)(Vws + (size_t)tb * 8 * 128);
    #pragma unroll
    for (int r = 0; r < 2; ++r) {
        int idx = r * 256 + tid;       // 0..511
        int row = idx >> 6;
        int c4  = idx & 63;
        *(float4*)&sva[row][c4 * 2] = srcA[idx];
        *(float4*)&svb[row][c4 * 2] = srcB[idx];
    }
    __syncthreads();

    const int p   = tid >> 3;        // pair 0..31 (8-lane aligned groups)
    const int sub = tid & 7;
    const int h   = sub & 1;         // row half       (dpp xor1 partner)
    const int e   = (sub >> 1) & 1;  // delta7 half    (dpp xor2 partner)
    const int f   = sub >> 2;        // m-half + delta6 half (swizzle xor4 partner)
    const int pa  = (hb << 2) | (p >> 3);   // 0..7
    const int pb  = p & 7;

    // ---- build own 2 rows of G = Va^H Vb, m-half only (split by f) ----
    v2f Go[2][8];
    #pragma unroll
    for (int i = 0; i < 2; ++i)
        #pragma unroll
        for (int j = 0; j < 8; ++j) Go[i][j] = (v2f){0.f, 0.f};

    const int mbase = f * 8;
    #pragma unroll
    for (int m = 0; m < 8; ++m) {
        const int mm = mbase + m;
        float4 va4 = *(const float4*)&sva[pa][mm * 8 + 4 * h + 2 * e];
        v2f a0 = {va4.x, va4.y};
        v2f a1 = {va4.z, va4.w};
        v2f vb[8];
        #pragma unroll
        for (int jj = 0; jj < 4; ++jj) {
            float4 b4 = *(const float4*)&svb[pb][mm * 8 + 2 * jj];
            vb[2 * jj]     = (v2f){b4.x, b4.y};
            vb[2 * jj + 1] = (v2f){b4.z, b4.w};
        }
        #pragma unroll
        for (int j = 0; j < 8; ++j) {
            Go[0][j] = cfma_conj(a0, vb[j], Go[0][j]);
            Go[1][j] = cfma_conj(a1, vb[j], Go[1][j]);
        }
    }

    // ---- combine the two m-halves across the f bit (xor 4, LDS swizzle) ----
    #pragma unroll
    for (int i = 0; i < 2; ++i)
        #pragma unroll
        for (int j = 0; j < 8; ++j) {
            Go[i][j].x += swz_xor4(Go[i][j].x);
            Go[i][j].y += swz_xor4(Go[i][j].y);
        }

    // ---- exchange 2 rows with e-partner (xor 2) via DPP ----
    v2f Gp[2][8];
    #pragma unroll
    for (int i = 0; i < 2; ++i)
        #pragma unroll
        for (int j = 0; j < 8; ++j) {
            Gp[i][j].x = dpp_xor2(Go[i][j].x);
            Gp[i][j].y = dpp_xor2(Go[i][j].y);
        }

    // ---- rs init: delta = (+1,...,+1, sgn_f @ col6, sgn_e @ col7) ----
    const float sgne = 1.0f - 2.0f * (float)e;
    const float sgnf = 1.0f - 2.0f * (float)f;
    const v2f sev = {sgne, sgne};
    const v2f sfv = {sgnf, sgnf};
    v2f rs[4];
    #pragma unroll
    for (int r = 0; r < 2; ++r) {
        {
            v2f s = ((Go[r][0] + Go[r][1]) + (Go[r][2] + Go[r][3]))
                  + (Go[r][4] + Go[r][5]);
            s = sfv * Go[r][6] + s;
            rs[r] = sev * Go[r][7] + s;
        }
        {
            v2f s = ((Gp[r][0] + Gp[r][1]) + (Gp[r][2] + Gp[r][3]))
                  + (Gp[r][4] + Gp[r][5]);
            s = sfv * Gp[r][6] + s;
            rs[2 + r] = sev * Gp[r][7] + s;
        }
    }

    v2f acc;

#define TREE(OUT) do {                                                \
        v2f t01 = cmul(rs[0], rs[1]);                                 \
        v2f t23 = cmul(rs[2], rs[3]);                                 \
        v2f half_ = cmul(t01, t23);                                   \
        v2f oth;                                                      \
        oth.x = dpp_xor1(half_.x);                                    \
        oth.y = dpp_xor1(half_.y);                                    \
        OUT = cmul(half_, oth);                                       \
    } while (0)

#define UPD(J, S) do {                                                \
        const v2f sv = {(S), (S)};                                    \
        rs[0] = sv * Go[0][J] + rs[0];                                \
        rs[1] = sv * Go[1][J] + rs[1];                                \
        rs[2] = sv * Gp[0][J] + rs[2];                                \
        rs[3] = sv * Gp[1][J] + rs[3];                                \
    } while (0)

#define TERM(TS) do {                                                 \
        v2f fullp; TREE(fullp);                                       \
        const v2f tv = {(TS), (TS)};                                  \
        acc = tv * fullp + acc;                                       \
    } while (0)

    // 32-term Gray ladder over delta1..delta5 (verified in round 2)
    TREE(acc);                              // t=0, sign +
    UPD(1, -2.f); TERM(-1.f);               // t=1
    UPD(2, -2.f); TERM( 1.f);               // t=2
    UPD(1,  2.f); TERM(-1.f);               // t=3
    UPD(3, -2.f); TERM( 1.f);               // t=4
    UPD(1, -2.f); TERM(-1.f);               // t=5
    UPD(2,  2.f); TERM( 1.f);               // t=6
    UPD(1,  2.f); TERM(-1.f);               // t=7
    UPD(4, -2.f); TERM( 1.f);               // t=8
    UPD(1, -2.f); TERM(-1.f);               // t=9
    UPD(2, -2.f); TERM( 1.f);               // t=10
    UPD(1,  2.f); TERM(-1.f);               // t=11
    UPD(3,  2.f); TERM( 1.f);               // t=12
    UPD(1, -2.f); TERM(-1.f);               // t=13
    UPD(2,  2.f); TERM( 1.f);               // t=14
    UPD(1,  2.f); TERM(-1.f);               // t=15
    UPD(5, -2.f); TERM( 1.f);               // t=16
    UPD(1, -2.f); TERM(-1.f);               // t=17
    UPD(2, -2.f); TERM( 1.f);               // t=18
    UPD(1,  2.f); TERM(-1.f);               // t=19
    UPD(3, -2.f); TERM( 1.f);               // t=20
    UPD(1, -2.f); TERM(-1.f);               // t=21
    UPD(2,  2.f); TERM( 1.f);               // t=22
    UPD(1,  2.f); TERM(-1.f);               // t=23
    UPD(4,  2.f); TERM( 1.f);               // t=24
    UPD(1, -2.f); TERM(-1.f);               // t=25
    UPD(2, -2.f); TERM( 1.f);               // t=26
    UPD(1,  2.f); TERM(-1.f);               // t=27
    UPD(3,  2.f); TERM( 1.f);               // t=28
    UPD(1, -2.f); TERM(-1.f);               // t=29
    UPD(2,  2.f); TERM( 1.f);               // t=30
    UPD(1,  2.f); TERM(-1.f);               // t=31
#undef UPD
#undef TERM
#undef TREE

    // fold delta6*delta7 coefficient, then sum the four (e,f) lane variants:
    // e via DPP xor2, f via ds_swizzle xor4.
    const float cf = sgne * sgnf;
    float ax = cf * acc.x, ay = cf * acc.y;
    ax += dpp_xor2(ax);
    ay += dpp_xor2(ay);
    ax += swz_xor4(ax);
    ay += swz_xor4(ay);

    if (sub == 0) {
        const int a = ta * 8 + pa;
        const int b = tb * 8 + pb;
        float K = fmaf(ax, ax, ay * ay) * (1.0f / 16384.0f);
        if (a == b) K = 1.0f;
        outK[a * 256 + b] = K;
        outK[b * 256 + a] = K;   // Hermitian symmetry
    }
}

extern "C" void kernel_launch(void* const* d_in, const int* in_sizes, int n_in,
                              void* d_out, int out_size, void* d_ws, size_t ws_size,
                              hipStream_t stream) {
    const float* x    = (const float*)d_in[0];   // 256*64
    const float* W    = (const float*)d_in[1];   // 120*64
    const float* bias = (const float*)d_in[2];   // 120
    float* out     = (float*)d_out;
    float* out_emb = out;              // 256*120
    float* outK    = out + NS * EMB;   // 256*256
    float2* Vws    = (float2*)d_ws;    // 256*16*8 float2 = 256 KB

    emb_v_kernel<<<NS, 128, 0, stream>>>(x, W, bias, out_emb, Vws);
    perm_kernel<<<1056, 256, 0, stream>>>(Vws, outK);
}

// Round 8
// 74.773 us; speedup vs baseline: 1.3773x; 1.0051x over previous
//
#include <hip/hip_runtime.h>
#include <math.h>

#define NS 256
#define EMB 120
#define NBLK 60
#define MODES 16
#define NPH 8

typedef float v2f __attribute__((ext_vector_type(2)));

// complex mul
__device__ __forceinline__ v2f cmul(v2f a, v2f b) {
    v2f axx = {a.x, a.x};
    v2f nyy = {-a.y, a.y};
    v2f byx = {b.y, b.x};
    return axx * b + nyy * byx;   // {ax*bx - ay*by, ax*by + ay*bx}
}
// r = conj(a)*b + c
__device__ __forceinline__ v2f cfma_conj(v2f a, v2f b, v2f c) {
    v2f axx = {a.x, a.x};
    v2f pyy = {a.y, -a.y};
    v2f byx = {b.y, b.x};
    return axx * b + (pyy * byx + c);
}

// Cross-lane xor within quad via DPP quad_perm (VALU, not LDS pipe).
// xor1: [1,0,3,2] -> ctrl 0xB1 ; xor2: [2,3,0,1] -> ctrl 0x4E
__device__ __forceinline__ float dpp_xor1(float x) {
    return __builtin_bit_cast(float,
        __builtin_amdgcn_mov_dpp(__builtin_bit_cast(int, x), 0xB1, 0xF, 0xF, true));
}
__device__ __forceinline__ float dpp_xor2(float x) {
    return __builtin_bit_cast(float,
        __builtin_amdgcn_mov_dpp(__builtin_bit_cast(int, x), 0x4E, 0xF, 0xF, true));
}
// xor4 crosses quads: ds_swizzle butterfly, offset = (xor_mask<<10)|0x1F
__device__ __forceinline__ float swz_xor4(float x) {
    return __builtin_bit_cast(float,
        __builtin_amdgcn_ds_swizzle(__builtin_bit_cast(int, x), 0x101F));
}

// Kernel A: R6 structure, ONE change — libm transcendental CALLS replaced by
// native HW instructions (__expf -> v_exp_f32, __sinf/__cosf -> v_sin/v_cos).
// Session algebra pins emb at ~13us vs ~3us of arithmetic, insensitive to
// load patterns (R4 A/B) -- the OCML sincosf/expf call sequences at 1-2
// waves/SIMD occupancy are the only untested load-independent candidate.
// Args are tiny (theta in (0,pi/2), phi in (0,2pi)): no range reduction
// needed; native precision ~1e-5 << the 2e-2 harness threshold.
__global__ __launch_bounds__(128) void emb_v_kernel(
    const float* __restrict__ x, const float* __restrict__ W,
    const float* __restrict__ bias, float* __restrict__ out_emb,
    float2* __restrict__ Vws)
{
    const int s = blockIdx.x;
    const int t = threadIdx.x;
    __shared__ float emb[EMB];
    __shared__ float ctA[NBLK], stA[NBLK], exA[NBLK], eyA[NBLK];

    if (t < EMB) {
        const float* xr = x + s * 64;
        const float* wr = W + t * 64;
        float acc = bias[t];
        #pragma unroll
        for (int k = 0; k < 64; ++k) acc = fmaf(xr[k], wr[k], acc);
        float e = 1.0f / (1.0f + __expf(-acc));   // native v_exp_f32 path
        emb[t] = e;
        out_emb[s * EMB + t] = e;
    }
    __syncthreads();

    if (t < NBLK) {
        float th = emb[2 * t]     * 1.57079632679489662f;  // pi/2
        float ph = emb[2 * t + 1] * 6.28318530717958648f;  // 2*pi
        float st = __sinf(th), ct = __cosf(th);            // native v_sin/v_cos
        float sp = __sinf(ph), cp = __cosf(ph);
        ctA[t] = ct; stA[t] = st; exA[t] = cp; eyA[t] = sp;
    }
    __syncthreads();

    if (t < NPH) {
        const int c = t;  // column 0..7
        float2 u[MODES];
        #pragma unroll
        for (int m = 0; m < MODES; ++m) {
            u[m].x = (m == c) ? 1.0f : 0.0f;
            u[m].y = 0.0f;
        }
        int bi = 0;
        #pragma unroll
        for (int d = 0; d < 8; ++d) {
            const int off = d & 1;
            const int nb = 8 - off;
            #pragma unroll
            for (int k = 0; k < nb; ++k) {
                float ct = ctA[bi], st = stA[bi], ex = exA[bi], ey = eyA[bi];
                ++bi;
                const int r0 = off + 2 * k;
                float2 u0 = u[r0], u1 = u[r0 + 1];
                float2 n0, n1;
                n0.x = ex * ct * u0.x - ey * ct * u0.y - st * u1.x;
                n0.y = ex * ct * u0.y + ey * ct * u0.x - st * u1.y;
                n1.x = ex * st * u0.x - ey * st * u0.y + ct * u1.x;
                n1.y = ex * st * u0.y + ey * st * u0.x + ct * u1.y;
                u[r0] = n0; u[r0 + 1] = n1;
            }
        }
        #pragma unroll
        for (int m = 0; m < MODES; ++m)
            Vws[(s * MODES + m) * NPH + c] = u[m];
    }
}

// Kernel B: byte-identical to round 6 (best measured: 75.15us total).
// 8 lanes/pair, dedup'd G-build (f splits m-halves), 32-term Gray ladder.
__global__ __launch_bounds__(256, 4) void perm_kernel(
    const float2* __restrict__ Vws, float* __restrict__ outK)
{
    __shared__ float2 sva[8][132];
    __shared__ float2 svb[8][132];

    // triangular decode: blockIdx>>1 -> (ta, tb), ta <= tb; blockIdx&1 -> pa half
    const int L  = blockIdx.x >> 1;
    const int hb = blockIdx.x & 1;
    int t = (int)((65.0f - sqrtf(4225.0f - 8.0f * (float)L)) * 0.5f);
    while (t * (65 - t) / 2 > L) --t;
    while ((t + 1) * (65 - (t + 1)) / 2 <= L) ++t;
    const int ta = t;
    const int tb = ta + (L - t * (65 - t) / 2);

    const int tid = threadIdx.x;
    const float4* srcA = (const float4*)(Vws + (size_t)ta * 8 * 128);
    const float4* srcB = (const float4*)(Vws + (size_t)tb * 8 * 128);
    #pragma unroll
    for (int r = 0; r < 2; ++r) {
        int idx = r * 256 + tid;       // 0..511
        int row = idx >> 6;
        int c4  = idx & 63;
        *(float4*)&sva[row][c4 * 2] = srcA[idx];
        *(float4*)&svb[row][c4 * 2] = srcB[idx];
    }
    __syncthreads();

    const int p   = tid >> 3;        // pair 0..31 (8-lane aligned groups)
    const int sub = tid & 7;
    const int h   = sub & 1;         // row half       (dpp xor1 partner)
    const int e   = (sub >> 1) & 1;  // delta7 half    (dpp xor2 partner)
    const int f   = sub >> 2;        // m-half + delta6 half (swizzle xor4 partner)
    const int pa  = (hb << 2) | (p >> 3);   // 0..7
    const int pb  = p & 7;

    // ---- build own 2 rows of G = Va^H Vb, m-half only (split by f) ----
    v2f Go[2][8];
    #pragma unroll
    for (int i = 0; i < 2; ++i)
        #pragma unroll
        for (int j = 0; j < 8; ++j) Go[i][j] = (v2f){0.f, 0.f};

    const int mbase = f * 8;
    #pragma unroll
    for (int m = 0; m < 8; ++m) {
        const int mm = mbase + m;
        float4 va4 = *(const float4*)&sva[pa][mm * 8 + 4 * h + 2 * e];
        v2f a0 = {va4.x, va4.y};
        v2f a1 = {va4.z, va4.w};
        v2f vb[8];
        #pragma unroll
        for (int jj = 0; jj < 4; ++jj) {
            float4 b4 = *(const float4*)&svb[pb][mm * 8 + 2 * jj];
            vb[2 * jj]     = (v2f){b4.x, b4.y};
            vb[2 * jj + 1] = (v2f){b4.z, b4.w};
        }
        #pragma unroll
        for (int j = 0; j < 8; ++j) {
            Go[0][j] = cfma_conj(a0, vb[j], Go[0][j]);
            Go[1][j] = cfma_conj(a1, vb[j], Go[1][j]);
        }
    }

    // ---- combine the two m-halves across the f bit (xor 4, LDS swizzle) ----
    #pragma unroll
    for (int i = 0; i < 2; ++i)
        #pragma unroll
        for (int j = 0; j < 8; ++j) {
            Go[i][j].x += swz_xor4(Go[i][j].x);
            Go[i][j].y += swz_xor4(Go[i][j].y);
        }

    // ---- exchange 2 rows with e-partner (xor 2) via DPP ----
    v2f Gp[2][8];
    #pragma unroll
    for (int i = 0; i < 2; ++i)
        #pragma unroll
        for (int j = 0; j < 8; ++j) {
            Gp[i][j].x = dpp_xor2(Go[i][j].x);
            Gp[i][j].y = dpp_xor2(Go[i][j].y);
        }

    // ---- rs init: delta = (+1,...,+1, sgn_f @ col6, sgn_e @ col7) ----
    const float sgne = 1.0f - 2.0f * (float)e;
    const float sgnf = 1.0f - 2.0f * (float)f;
    const v2f sev = {sgne, sgne};
    const v2f sfv = {sgnf, sgnf};
    v2f rs[4];
    #pragma unroll
    for (int r = 0; r < 2; ++r) {
        {
            v2f s = ((Go[r][0] + Go[r][1]) + (Go[r][2] + Go[r][3]))
                  + (Go[r][4] + Go[r][5]);
            s = sfv * Go[r][6] + s;
            rs[r] = sev * Go[r][7] + s;
        }
        {
            v2f s = ((Gp[r][0] + Gp[r][1]) + (Gp[r][2] + Gp[r][3]))
                  + (Gp[r][4] + Gp[r][5]);
            s = sfv * Gp[r][6] + s;
            rs[2 + r] = sev * Gp[r][7] + s;
        }
    }

    v2f acc;

#define TREE(OUT) do {                                                \
        v2f t01 = cmul(rs[0], rs[1]);                                 \
        v2f t23 = cmul(rs[2], rs[3]);                                 \
        v2f half_ = cmul(t01, t23);                                   \
        v2f oth;                                                      \
        oth.x = dpp_xor1(half_.x);                                    \
        oth.y = dpp_xor1(half_.y);                                    \
        OUT = cmul(half_, oth);                                       \
    } while (0)

#define UPD(J, S) do {                                                \
        const v2f sv = {(S), (S)};                                    \
        rs[0] = sv * Go[0][J] + rs[0];                                \
        rs[1] = sv * Go[1][J] + rs[1];                                \
        rs[2] = sv * Gp[0][J] + rs[2];                                \
        rs[3] = sv * Gp[1][J] + rs[3];                                \
    } while (0)

#define TERM(TS) do {                                                 \
        v2f fullp; TREE(fullp);                                       \
        const v2f tv = {(TS), (TS)};                                  \
        acc = tv * fullp + acc;                                       \
    } while (0)

    // 32-term Gray ladder over delta1..delta5 (verified in rounds 2/6)
    TREE(acc);                              // t=0, sign +
    UPD(1, -2.f); TERM(-1.f);               // t=1
    UPD(2, -2.f); TERM( 1.f);               // t=2
    UPD(1,  2.f); TERM(-1.f);               // t=3
    UPD(3, -2.f); TERM( 1.f);               // t=4
    UPD(1, -2.f); TERM(-1.f);               // t=5
    UPD(2,  2.f); TERM( 1.f);               // t=6
    UPD(1,  2.f); TERM(-1.f);               // t=7
    UPD(4, -2.f); TERM( 1.f);               // t=8
    UPD(1, -2.f); TERM(-1.f);               // t=9
    UPD(2, -2.f); TERM( 1.f);               // t=10
    UPD(1,  2.f); TERM(-1.f);               // t=11
    UPD(3,  2.f); TERM( 1.f);               // t=12
    UPD(1, -2.f); TERM(-1.f);               // t=13
    UPD(2,  2.f); TERM( 1.f);               // t=14
    UPD(1,  2.f); TERM(-1.f);               // t=15
    UPD(5, -2.f); TERM( 1.f);               // t=16
    UPD(1, -2.f); TERM(-1.f);               // t=17
    UPD(2, -2.f); TERM( 1.f);               // t=18
    UPD(1,  2.f); TERM(-1.f);               // t=19
    UPD(3, -2.f); TERM( 1.f);               // t=20
    UPD(1, -2.f); TERM(-1.f);               // t=21
    UPD(2,  2.f); TERM( 1.f);               // t=22
    UPD(1,  2.f); TERM(-1.f);               // t=23
    UPD(4,  2.f); TERM( 1.f);               // t=24
    UPD(1, -2.f); TERM(-1.f);               // t=25
    UPD(2, -2.f); TERM( 1.f);               // t=26
    UPD(1,  2.f); TERM(-1.f);               // t=27
    UPD(3,  2.f); TERM( 1.f);               // t=28
    UPD(1, -2.f); TERM(-1.f);               // t=29
    UPD(2,  2.f); TERM( 1.f);               // t=30
    UPD(1,  2.f); TERM(-1.f);               // t=31
#undef UPD
#undef TERM
#undef TREE

    // fold delta6*delta7 coefficient, then sum the four (e,f) lane variants:
    // e via DPP xor2, f via ds_swizzle xor4.
    const float cf = sgne * sgnf;
    float ax = cf * acc.x, ay = cf * acc.y;
    ax += dpp_xor2(ax);
    ay += dpp_xor2(ay);
    ax += swz_xor4(ax);
    ay += swz_xor4(ay);

    if (sub == 0) {
        const int a = ta * 8 + pa;
        const int b = tb * 8 + pb;
        float K = fmaf(ax, ax, ay * ay) * (1.0f / 16384.0f);
        if (a == b) K = 1.0f;
        outK[a * 256 + b] = K;
        outK[b * 256 + a] = K;   // Hermitian symmetry
    }
}

extern "C" void kernel_launch(void* const* d_in, const int* in_sizes, int n_in,
                              void* d_out, int out_size, void* d_ws, size_t ws_size,
                              hipStream_t stream) {
    const float* x    = (const float*)d_in[0];   // 256*64
    const float* W    = (const float*)d_in[1];   // 120*64
    const float* bias = (const float*)d_in[2];   // 120
    float* out     = (float*)d_out;
    float* out_emb = out;              // 256*120
    float* outK    = out + NS * EMB;   // 256*256
    float2* Vws    = (float2*)d_ws;    // 256*16*8 float2 = 256 KB

    emb_v_kernel<<<NS, 128, 0, stream>>>(x, W, bias, out_emb, Vws);
    perm_kernel<<<1056, 256, 0, stream>>>(Vws, outK);
}